// Round 4
// baseline (413.830 us; speedup 1.0000x reference)
//
#include <hip/hip_runtime.h>
#include <math.h>

#define NN 8192
#define FF 256
#define MAXN 128   // max neighbors/row; Binomial(8192,0.004) max ~62 incl. self-loop

// ---------------------------------------------------------------------------
// K1: Xp = X @ W^T + b.  64x64x64 tiles, transposed LDS [k][row],
// register-prefetch double buffer (global loads overlap the FMA loop).
// ---------------------------------------------------------------------------
__global__ __launch_bounds__(256) void gemm_kernel(const float* __restrict__ X,
                                                   const float* __restrict__ W,
                                                   const float* __restrict__ bias,
                                                   float* __restrict__ Xp) {
    __shared__ float Xs[64][64];
    __shared__ float Ws[64][64];
    const int tid  = threadIdx.x;
    const int row0 = blockIdx.x * 64;
    const int col0 = blockIdx.y * 64;
    const int ty   = tid >> 4;      // 0..15 -> 4 output rows each
    const int tx   = tid & 15;      // 0..15 -> 4 output cols each
    const int lrow = tid & 63;      // staging row within tile
    const int kq0  = (tid >> 6) * 4;

    const float* Xr = &X[(size_t)(row0 + lrow) * FF];
    const float* Wr = &W[(size_t)(col0 + lrow) * FF];

    float4 px[4], pw[4];
#pragma unroll
    for (int q = 0; q < 4; ++q) {
        px[q] = *reinterpret_cast<const float4*>(&Xr[(kq0 + q) * 4]);
        pw[q] = *reinterpret_cast<const float4*>(&Wr[(kq0 + q) * 4]);
    }

    float acc[4][4] = {};

#pragma unroll
    for (int kt = 0; kt < 4; ++kt) {
        // store prefetched tile -> LDS (transposed [k][row]; consecutive lanes
        // -> consecutive banks, conflict-free)
#pragma unroll
        for (int q = 0; q < 4; ++q) {
            const int k0 = (kq0 + q) * 4;
            Xs[k0+0][lrow]=px[q].x; Xs[k0+1][lrow]=px[q].y; Xs[k0+2][lrow]=px[q].z; Xs[k0+3][lrow]=px[q].w;
            Ws[k0+0][lrow]=pw[q].x; Ws[k0+1][lrow]=pw[q].y; Ws[k0+2][lrow]=pw[q].z; Ws[k0+3][lrow]=pw[q].w;
        }
        __syncthreads();
        if (kt < 3) {  // issue next tile's global loads before the FMA loop
            const int kb = (kt + 1) * 64;
#pragma unroll
            for (int q = 0; q < 4; ++q) {
                px[q] = *reinterpret_cast<const float4*>(&Xr[kb + (kq0 + q) * 4]);
                pw[q] = *reinterpret_cast<const float4*>(&Wr[kb + (kq0 + q) * 4]);
            }
        }
#pragma unroll 8
        for (int k = 0; k < 64; ++k) {
            const float4 a4 = *reinterpret_cast<const float4*>(&Xs[k][ty * 4]);
            const float4 b4 = *reinterpret_cast<const float4*>(&Ws[k][tx * 4]);
            const float av[4] = {a4.x, a4.y, a4.z, a4.w};
            const float bv[4] = {b4.x, b4.y, b4.z, b4.w};
#pragma unroll
            for (int ii = 0; ii < 4; ++ii)
#pragma unroll
                for (int jj = 0; jj < 4; ++jj)
                    acc[ii][jj] = fmaf(av[ii], bv[jj], acc[ii][jj]);
        }
        __syncthreads();
    }

    const float4 b4 = *reinterpret_cast<const float4*>(&bias[col0 + tx * 4]);
#pragma unroll
    for (int ii = 0; ii < 4; ++ii) {
        const int r = row0 + ty * 4 + ii;
        float4 o;
        o.x = acc[ii][0] + b4.x;
        o.y = acc[ii][1] + b4.y;
        o.z = acc[ii][2] + b4.z;
        o.w = acc[ii][3] + b4.w;
        *reinterpret_cast<float4*>(&Xp[(size_t)r * FF + col0 + tx * 4]) = o;
    }
}

// ---------------------------------------------------------------------------
// K2: a_src[i] = Xp[i,:].S[0:FF],  a_dst[i] = Xp[i,:].S[FF:2FF]. Wave per row.
// ---------------------------------------------------------------------------
__global__ __launch_bounds__(256) void dots_kernel(const float* __restrict__ Xp,
                                                   const float* __restrict__ S,
                                                   float* __restrict__ a_src,
                                                   float* __restrict__ a_dst) {
    const int wid  = threadIdx.x >> 6;
    const int lane = threadIdx.x & 63;
    const int row  = blockIdx.x * 4 + wid;
    const float4 xv = *reinterpret_cast<const float4*>(&Xp[(size_t)row * FF + lane * 4]);
    const float4 s0 = *reinterpret_cast<const float4*>(&S[lane * 4]);
    const float4 s1 = *reinterpret_cast<const float4*>(&S[FF + lane * 4]);
    float ps = xv.x * s0.x + xv.y * s0.y + xv.z * s0.z + xv.w * s0.w;
    float pd = xv.x * s1.x + xv.y * s1.y + xv.z * s1.z + xv.w * s1.w;
#pragma unroll
    for (int off = 32; off; off >>= 1) {
        ps += __shfl_xor(ps, off);
        pd += __shfl_xor(pd, off);
    }
    if (lane == 0) {
        a_src[row] = ps;
        a_dst[row] = pd;
    }
}

// ---------------------------------------------------------------------------
// K3 (pass 1): per row i, stream the adj row (the ONLY big HBM read), compact
// neighbor list, softmax over leaky_relu(a_src[i]+a_dst[j]) incl. forced
// self-loop, write normalized weights + indices to CSR in ws.
// Only small tables (a_dst: 32 KB) are gathered here -> stays HBM-BW-bound.
// ---------------------------------------------------------------------------
__global__ __launch_bounds__(256) void csr_kernel(const float* __restrict__ adj,
                                                  const float* __restrict__ a_src,
                                                  const float* __restrict__ a_dst,
                                                  int* __restrict__ cnt_g,
                                                  int* __restrict__ nbr_g,
                                                  float* __restrict__ wt_g) {
    __shared__ int   nbr_s[MAXN];
    __shared__ float redm[4];
    __shared__ float reds[4];
    __shared__ int   cnt;

    const int i = blockIdx.x;
    const int t = threadIdx.x;
    if (t == 0) cnt = 0;
    __syncthreads();

    const size_t base = (size_t)i * NN;
#pragma unroll
    for (int it = 0; it < NN / 1024; ++it) {
        const int c0 = it * 1024 + t * 4;
        const float4 v = *reinterpret_cast<const float4*>(&adj[base + c0]);
        const float vv[4] = {v.x, v.y, v.z, v.w};
#pragma unroll
        for (int u = 0; u < 4; ++u) {
            const int col = c0 + u;
            if (vv[u] != 0.f || col == i) {  // (adj!=0 | eye): single mask, no dedupe issue
                const int slot = atomicAdd(&cnt, 1);
                if (slot < MAXN) nbr_s[slot] = col;
            }
        }
    }
    __syncthreads();

    const int n = min(cnt, MAXN);
    const float si = a_src[i];
    int   j  = 0;
    float ev = -INFINITY;
    if (t < n) {
        j = nbr_s[t];
        const float x = si + a_dst[j];
        ev = (x >= 0.f) ? x : 0.01f * x;     // jax leaky_relu default slope
    }

    float m = ev;
#pragma unroll
    for (int off = 32; off; off >>= 1) m = fmaxf(m, __shfl_xor(m, off));
    if ((t & 63) == 0) redm[t >> 6] = m;
    __syncthreads();
    m = fmaxf(fmaxf(redm[0], redm[1]), fmaxf(redm[2], redm[3]));

    const float w = (t < n) ? __expf(ev - m) : 0.f;
    float s = w;
#pragma unroll
    for (int off = 32; off; off >>= 1) s += __shfl_xor(s, off);
    if ((t & 63) == 0) reds[t >> 6] = s;
    __syncthreads();
    const float inv_den = 1.f / (reds[0] + reds[1] + reds[2] + reds[3]);

    if (t < n) {
        nbr_g[(size_t)i * MAXN + t] = j;
        wt_g [(size_t)i * MAXN + t] = w * inv_den;
    }
    if (t == 0) cnt_g[i] = n;
}

// ---------------------------------------------------------------------------
// K4 (pass 2): out[i,:] = sigmoid( sum_k wt[k] * Xp[nbr[k],:] ).
// One wave per row; lane owns a float4 feature chunk (coalesced 1 KB per
// neighbor row). Xp (8 MB) is L2/L3-resident now that nothing streams.
// ---------------------------------------------------------------------------
__global__ __launch_bounds__(256) void agg_kernel(const int* __restrict__ cnt_g,
                                                  const int* __restrict__ nbr_g,
                                                  const float* __restrict__ wt_g,
                                                  const float* __restrict__ Xp,
                                                  float* __restrict__ out) {
    __shared__ int   nb[4][MAXN];
    __shared__ float wt[4][MAXN];

    const int wid  = threadIdx.x >> 6;
    const int lane = threadIdx.x & 63;
    const int i    = blockIdx.x * 4 + wid;

    const int n = cnt_g[i];
    if (lane < n) {
        nb[wid][lane] = nbr_g[(size_t)i * MAXN + lane];
        wt[wid][lane] = wt_g [(size_t)i * MAXN + lane];
    }
    if (lane + 64 < n) {
        nb[wid][lane + 64] = nbr_g[(size_t)i * MAXN + lane + 64];
        wt[wid][lane + 64] = wt_g [(size_t)i * MAXN + lane + 64];
    }
    __syncthreads();

    const float* xb = Xp + lane * 4;
    float4 acc = {0.f, 0.f, 0.f, 0.f};
    int k = 0;
    for (; k + 2 <= n; k += 2) {
        const int   j0 = nb[wid][k],     j1 = nb[wid][k + 1];
        const float w0 = wt[wid][k],     w1 = wt[wid][k + 1];
        const float4 v0 = *reinterpret_cast<const float4*>(&xb[(size_t)j0 * FF]);
        const float4 v1 = *reinterpret_cast<const float4*>(&xb[(size_t)j1 * FF]);
        acc.x += w0 * v0.x + w1 * v1.x;
        acc.y += w0 * v0.y + w1 * v1.y;
        acc.z += w0 * v0.z + w1 * v1.z;
        acc.w += w0 * v0.w + w1 * v1.w;
    }
    if (k < n) {
        const int   j0 = nb[wid][k];
        const float w0 = wt[wid][k];
        const float4 v0 = *reinterpret_cast<const float4*>(&xb[(size_t)j0 * FF]);
        acc.x += w0 * v0.x; acc.y += w0 * v0.y; acc.z += w0 * v0.z; acc.w += w0 * v0.w;
    }

    float4 o;
    o.x = 1.f / (1.f + __expf(-acc.x));
    o.y = 1.f / (1.f + __expf(-acc.y));
    o.z = 1.f / (1.f + __expf(-acc.z));
    o.w = 1.f / (1.f + __expf(-acc.w));
    *reinterpret_cast<float4*>(&out[(size_t)i * FF + lane * 4]) = o;
}

// ---------------------------------------------------------------------------
extern "C" void kernel_launch(void* const* d_in, const int* in_sizes, int n_in,
                              void* d_out, int out_size, void* d_ws, size_t ws_size,
                              hipStream_t stream) {
    const float* X   = (const float*)d_in[0];
    const float* adj = (const float*)d_in[1];
    const float* W   = (const float*)d_in[2];
    const float* b   = (const float*)d_in[3];
    const float* S   = (const float*)d_in[4];
    float* out = (float*)d_out;

    float* Xp    = (float*)d_ws;                       // 8 MB
    float* a_src = Xp + (size_t)NN * FF;               // 32 KB
    float* a_dst = a_src + NN;                         // 32 KB
    int*   cnt_g = (int*)(a_dst + NN);                 // 32 KB
    int*   nbr_g = cnt_g + NN;                         // 4 MB
    float* wt_g  = (float*)(nbr_g + (size_t)NN * MAXN);// 4 MB

    gemm_kernel<<<dim3(NN / 64, FF / 64), 256, 0, stream>>>(X, W, b, Xp);
    dots_kernel<<<NN / 4, 256, 0, stream>>>(Xp, S, a_src, a_dst);
    csr_kernel<<<NN, 256, 0, stream>>>(adj, a_src, a_dst, cnt_g, nbr_g, wt_g);
    agg_kernel<<<NN / 4, 256, 0, stream>>>(cnt_g, nbr_g, wt_g, Xp, out);
}

// Round 5
// 398.416 us; speedup vs baseline: 1.0387x; 1.0387x over previous
//
#include <hip/hip_runtime.h>
#include <math.h>

#define NN 8192
#define FF 256
#define MAXN 128            // max degree incl. self-loop; Binomial(8191,0.004) max ~60
#define NGEMM ((NN / 64) * (FF / 64))   // 512 gemm blocks

// ---------------------------------------------------------------------------
// K1: heterogeneous blocks.
//   blocks [0, NGEMM)        : Xp = X @ W^T + b   (64x64x64 tiles, LDS-transposed,
//                              register-prefetch double buffer)
//   blocks [NGEMM, NGEMM+NN) : scan adj row i -> compacted neighbor indices
//                              (load-all-then-process: 8 float4 in flight/wave)
// The two groups are data-independent; memory-bound scan overlaps compute-bound GEMM.
// ---------------------------------------------------------------------------
__global__ __launch_bounds__(256) void gemm_scan_kernel(const float* __restrict__ X,
                                                        const float* __restrict__ W,
                                                        const float* __restrict__ bias,
                                                        const float* __restrict__ adj,
                                                        float* __restrict__ Xp,
                                                        int* __restrict__ cnt_g,
                                                        int* __restrict__ nbr_g) {
    __shared__ float Xs[64][64];
    __shared__ float Ws[64][64];
    __shared__ int   nbr_s[MAXN];
    __shared__ int   cnt;

    const int tid = threadIdx.x;

    if (blockIdx.x < NGEMM) {
        // ---------------- GEMM path ----------------
        const int rt   = blockIdx.x >> 2;       // 0..127 row tile
        const int ct   = blockIdx.x & 3;        // 0..3   col tile
        const int row0 = rt * 64;
        const int col0 = ct * 64;
        const int ty   = tid >> 4;              // 4 output rows each
        const int tx   = tid & 15;              // 4 output cols each
        const int lrow = tid & 63;
        const int kq0  = (tid >> 6) * 4;

        const float* Xr = &X[(size_t)(row0 + lrow) * FF];
        const float* Wr = &W[(size_t)(col0 + lrow) * FF];

        float4 px[4], pw[4];
#pragma unroll
        for (int q = 0; q < 4; ++q) {
            px[q] = *reinterpret_cast<const float4*>(&Xr[(kq0 + q) * 4]);
            pw[q] = *reinterpret_cast<const float4*>(&Wr[(kq0 + q) * 4]);
        }

        float acc[4][4] = {};

#pragma unroll
        for (int kt = 0; kt < 4; ++kt) {
#pragma unroll
            for (int q = 0; q < 4; ++q) {
                const int k0 = (kq0 + q) * 4;
                Xs[k0+0][lrow]=px[q].x; Xs[k0+1][lrow]=px[q].y; Xs[k0+2][lrow]=px[q].z; Xs[k0+3][lrow]=px[q].w;
                Ws[k0+0][lrow]=pw[q].x; Ws[k0+1][lrow]=pw[q].y; Ws[k0+2][lrow]=pw[q].z; Ws[k0+3][lrow]=pw[q].w;
            }
            __syncthreads();
            if (kt < 3) {
                const int kb = (kt + 1) * 64;
#pragma unroll
                for (int q = 0; q < 4; ++q) {
                    px[q] = *reinterpret_cast<const float4*>(&Xr[kb + (kq0 + q) * 4]);
                    pw[q] = *reinterpret_cast<const float4*>(&Wr[kb + (kq0 + q) * 4]);
                }
            }
#pragma unroll 8
            for (int k = 0; k < 64; ++k) {
                const float4 a4 = *reinterpret_cast<const float4*>(&Xs[k][ty * 4]);
                const float4 b4 = *reinterpret_cast<const float4*>(&Ws[k][tx * 4]);
                const float av[4] = {a4.x, a4.y, a4.z, a4.w};
                const float bv[4] = {b4.x, b4.y, b4.z, b4.w};
#pragma unroll
                for (int ii = 0; ii < 4; ++ii)
#pragma unroll
                    for (int jj = 0; jj < 4; ++jj)
                        acc[ii][jj] = fmaf(av[ii], bv[jj], acc[ii][jj]);
            }
            __syncthreads();
        }

        const float4 b4 = *reinterpret_cast<const float4*>(&bias[col0 + tx * 4]);
#pragma unroll
        for (int ii = 0; ii < 4; ++ii) {
            const int r = row0 + ty * 4 + ii;
            float4 o;
            o.x = acc[ii][0] + b4.x;
            o.y = acc[ii][1] + b4.y;
            o.z = acc[ii][2] + b4.z;
            o.w = acc[ii][3] + b4.w;
            *reinterpret_cast<float4*>(&Xp[(size_t)r * FF + col0 + tx * 4]) = o;
        }
    } else {
        // ---------------- adjacency scan path ----------------
        const int i = blockIdx.x - NGEMM;
        if (tid == 0) cnt = 0;
        __syncthreads();

        const size_t base = (size_t)i * NN;
        float4 v[8];
#pragma unroll
        for (int it = 0; it < 8; ++it)       // issue all 8 loads first (8 KB/wave in flight)
            v[it] = *reinterpret_cast<const float4*>(&adj[base + it * 1024 + tid * 4]);
#pragma unroll
        for (int it = 0; it < 8; ++it) {
            const int c0 = it * 1024 + tid * 4;
            const float vv[4] = {v[it].x, v[it].y, v[it].z, v[it].w};
#pragma unroll
            for (int u = 0; u < 4; ++u) {
                const int col = c0 + u;
                if (vv[u] != 0.f || col == i) {   // (adj!=0 | eye): one mask, no dedupe
                    const int slot = atomicAdd(&cnt, 1);
                    if (slot < MAXN) nbr_s[slot] = col;
                }
            }
        }
        __syncthreads();
        const int n = min(cnt, MAXN);
        if (tid < n) nbr_g[(size_t)i * MAXN + tid] = nbr_s[tid];
        if (tid == 0) cnt_g[i] = n;
    }
}

// ---------------------------------------------------------------------------
// K2: a_src[i] = Xp[i,:].S[0:FF],  a_dst[i] = Xp[i,:].S[FF:2FF]. Wave per row.
// ---------------------------------------------------------------------------
__global__ __launch_bounds__(256) void dots_kernel(const float* __restrict__ Xp,
                                                   const float* __restrict__ S,
                                                   float* __restrict__ a_src,
                                                   float* __restrict__ a_dst) {
    const int wid  = threadIdx.x >> 6;
    const int lane = threadIdx.x & 63;
    const int row  = blockIdx.x * 4 + wid;
    const float4 xv = *reinterpret_cast<const float4*>(&Xp[(size_t)row * FF + lane * 4]);
    const float4 s0 = *reinterpret_cast<const float4*>(&S[lane * 4]);
    const float4 s1 = *reinterpret_cast<const float4*>(&S[FF + lane * 4]);
    float ps = xv.x * s0.x + xv.y * s0.y + xv.z * s0.z + xv.w * s0.w;
    float pd = xv.x * s1.x + xv.y * s1.y + xv.z * s1.z + xv.w * s1.w;
#pragma unroll
    for (int off = 32; off; off >>= 1) {
        ps += __shfl_xor(ps, off);
        pd += __shfl_xor(pd, off);
    }
    if (lane == 0) {
        a_src[row] = ps;
        a_dst[row] = pd;
    }
}

// ---------------------------------------------------------------------------
// K3: per row i (wave per row, 4 rows/block):
//   softmax over leaky_relu(a_src[i] + a_dst[j]) for the compacted neighbor
//   set (self-loop included by construction), then
//   out[i,:] = sigmoid( sum_j attn_j * Xp[j,:] ), float4 per lane.
// ---------------------------------------------------------------------------
__global__ __launch_bounds__(256) void agg_kernel(const int* __restrict__ cnt_g,
                                                  const int* __restrict__ nbr_g,
                                                  const float* __restrict__ a_src,
                                                  const float* __restrict__ a_dst,
                                                  const float* __restrict__ Xp,
                                                  float* __restrict__ out) {
    __shared__ int   nb[4][MAXN];
    __shared__ float wt[4][MAXN];

    const int wid  = threadIdx.x >> 6;
    const int lane = threadIdx.x & 63;
    const int i    = blockIdx.x * 4 + wid;

    const int   n  = cnt_g[i];
    const float si = a_src[i];

    // lane handles neighbor slots {lane, lane+64}
    int   j0 = 0, j1 = 0;
    float e0 = -INFINITY, e1 = -INFINITY;
    if (lane < n) {
        j0 = nbr_g[(size_t)i * MAXN + lane];
        const float x = si + a_dst[j0];
        e0 = (x >= 0.f) ? x : 0.01f * x;     // jax leaky_relu default slope
    }
    if (lane + 64 < n) {
        j1 = nbr_g[(size_t)i * MAXN + lane + 64];
        const float x = si + a_dst[j1];
        e1 = (x >= 0.f) ? x : 0.01f * x;
    }

    float m = fmaxf(e0, e1);
#pragma unroll
    for (int off = 32; off; off >>= 1) m = fmaxf(m, __shfl_xor(m, off));

    const float w0 = (lane < n)      ? __expf(e0 - m) : 0.f;
    const float w1 = (lane + 64 < n) ? __expf(e1 - m) : 0.f;
    float s = w0 + w1;
#pragma unroll
    for (int off = 32; off; off >>= 1) s += __shfl_xor(s, off);
    const float inv_den = 1.f / s;

    nb[wid][lane]      = j0;
    wt[wid][lane]      = w0 * inv_den;
    nb[wid][lane + 64] = j1;
    wt[wid][lane + 64] = w1 * inv_den;
    __syncthreads();

    // weighted gather: lane owns features [4*lane, 4*lane+4)
    const float* xb = Xp + lane * 4;
    float4 acc = {0.f, 0.f, 0.f, 0.f};
    int k = 0;
    for (; k + 2 <= n; k += 2) {
        const int   g0 = nb[wid][k],     g1 = nb[wid][k + 1];
        const float u0 = wt[wid][k],     u1 = wt[wid][k + 1];
        const float4 v0 = *reinterpret_cast<const float4*>(&xb[(size_t)g0 * FF]);
        const float4 v1 = *reinterpret_cast<const float4*>(&xb[(size_t)g1 * FF]);
        acc.x += u0 * v0.x + u1 * v1.x;
        acc.y += u0 * v0.y + u1 * v1.y;
        acc.z += u0 * v0.z + u1 * v1.z;
        acc.w += u0 * v0.w + u1 * v1.w;
    }
    if (k < n) {
        const int   g0 = nb[wid][k];
        const float u0 = wt[wid][k];
        const float4 v0 = *reinterpret_cast<const float4*>(&xb[(size_t)g0 * FF]);
        acc.x += u0 * v0.x; acc.y += u0 * v0.y; acc.z += u0 * v0.z; acc.w += u0 * v0.w;
    }

    float4 o;
    o.x = 1.f / (1.f + __expf(-acc.x));
    o.y = 1.f / (1.f + __expf(-acc.y));
    o.z = 1.f / (1.f + __expf(-acc.z));
    o.w = 1.f / (1.f + __expf(-acc.w));
    *reinterpret_cast<float4*>(&out[(size_t)i * FF + lane * 4]) = o;
}

// ---------------------------------------------------------------------------
extern "C" void kernel_launch(void* const* d_in, const int* in_sizes, int n_in,
                              void* d_out, int out_size, void* d_ws, size_t ws_size,
                              hipStream_t stream) {
    const float* X   = (const float*)d_in[0];
    const float* adj = (const float*)d_in[1];
    const float* W   = (const float*)d_in[2];
    const float* b   = (const float*)d_in[3];
    const float* S   = (const float*)d_in[4];
    float* out = (float*)d_out;

    float* Xp    = (float*)d_ws;                        // 8 MB
    float* a_src = Xp + (size_t)NN * FF;                // 32 KB
    float* a_dst = a_src + NN;                          // 32 KB
    int*   cnt_g = (int*)(a_dst + NN);                  // 32 KB
    int*   nbr_g = cnt_g + NN;                          // 4 MB

    gemm_scan_kernel<<<NGEMM + NN, 256, 0, stream>>>(X, W, b, adj, Xp, cnt_g, nbr_g);
    dots_kernel<<<NN / 4, 256, 0, stream>>>(Xp, S, a_src, a_dst);
    agg_kernel<<<NN / 4, 256, 0, stream>>>(cnt_g, nbr_g, a_src, a_dst, Xp, out);
}